// Round 6
// baseline (1734.868 us; speedup 1.0000x reference)
//
#include <hip/hip_runtime.h>

#define CCH  512
#define HF   50
#define WF   50
#define NROI 256
#define WS_NEEDED (HF * WF * CCH * sizeof(float))   // 5.12 MB transposed map
#define ROWSTR (WF * 256)                           // floats between y rows (within cg256)
#define OBSTR 258                                   // LDS stage stride (floats)

// ---------- Kernel 1: transpose [C][H][W] -> [cg256][H][W][256] into ws ----------
__global__ __launch_bounds__(256) void transpose_kernel(
    const float* __restrict__ x, float* __restrict__ xt)
{
    __shared__ float tile[64][51];                 // odd stride: conflict-free
    const int y  = blockIdx.x >> 3;
    const int c0 = (blockIdx.x & 7) << 6;
    const int t  = threadIdx.x;
    const int wv = t >> 6, lane = t & 63;

    for (int r = 0; r < 16; ++r) {
        const int cl = wv * 16 + r;
        if (lane < WF)
            tile[cl][lane] = x[(c0 + cl) * (HF * WF) + y * WF + lane];
    }
    __syncthreads();

    const int g   = c0 >> 8;                       // 256-group id (0/1)
    const int cin = c0 & 255;
    for (int k = 0; k < 13; ++k) {
        const int xx = (t >> 6) + 4 * k;
        if (xx < WF)
            xt[((size_t)g * (HF * WF) + y * WF + xx) * 256 + cin + (t & 63)]
                = tile[t & 63][xx];
    }
}

// ---------- Kernel 2: pool from blocked-transposed map ----------
// Block = (n, cg of 256 channels): 512 blocks x 512 threads (8 waves).
// Lanes = channels via float4. Both window spans compile-time via 25-case
// switch: all loads of a task issue independently -> 1 latency exposure/task.
__global__ __launch_bounds__(512, 4) void roipool_t_kernel(
    const float* __restrict__ xt,
    const float* __restrict__ rois,
    float* __restrict__ out)
{
    __shared__ float ob[49 * OBSTR];               // 50.6 KB staged outputs

    const int n  = blockIdx.x >> 1;
    const int cg = blockIdx.x & 1;                 // == xcd&1: one 2.56MB L2 partition/XCD
    const int t  = threadIdx.x;
    const int wv = t >> 6, lane = t & 63;

    // scale 50/800 = 0.0625 exact; (int) trunc == jnp astype(int32)
    const float4 rv = *(const float4*)(rois + n * 4);
    const int rx = (int)(rv.x * 0.0625f);
    const int ry = (int)(rv.y * 0.0625f);
    const int sw = (int)(rv.z * 0.0625f) + 1;      // 6..23
    const int sh = (int)(rv.w * 0.0625f) + 1;      // 6..23

    const float* part = xt + (size_t)cg * (HF * WF * 256) + 4 * lane;

#define M4A(a) { m.x = fmaxf(m.x,(a).x); m.y = fmaxf(m.y,(a).y); \
                 m.z = fmaxf(m.z,(a).z); m.w = fmaxf(m.w,(a).w); }
#define BODY(YS,XS) { \
    _Pragma("unroll") \
    for (int yy = 0; yy < (YS); ++yy) { \
      _Pragma("unroll") \
      for (int xx = 0; xx < (XS); ++xx) { \
        float4 a = *(const float4*)(rp + yy * ROWSTR + xx * 256); \
        M4A(a); \
      } } }
#define XCASE(YS) switch (xspan) { \
    case 1: BODY(YS,1); break; \
    case 2: BODY(YS,2); break; \
    case 3: BODY(YS,3); break; \
    case 4: BODY(YS,4); break; \
    default: BODY(YS,5); break; }

    for (int task = wv; task < 49; task += 8) {
        const int ph = task / 7;
        const int pw = task - ph * 7;
        const int ys = ry + (ph * sh) / 7;
        const int ye = ry + ((ph + 1) * sh + 6) / 7;   // <= 47
        const int xs = rx + (pw * sw) / 7;
        const int xe = rx + ((pw + 1) * sw + 6) / 7;   // <= 47
        const int yspan = ye - ys;                     // 1..5 (proved from sh<=23)
        const int xspan = xe - xs;                     // 1..5
        const float* rp = part + (ys * WF + xs) * 256;

        float4 m = make_float4(-INFINITY, -INFINITY, -INFINITY, -INFINITY);
        switch (yspan) {                               // wave-uniform scalar branches
        case 1: XCASE(1); break;
        case 2: XCASE(2); break;
        case 3: XCASE(3); break;
        case 4: XCASE(4); break;
        default: XCASE(5); break;
        }

        *(float2*)&ob[task * OBSTR + 4 * lane]     = make_float2(m.x, m.y);
        *(float2*)&ob[task * OBSTR + 4 * lane + 2] = make_float2(m.z, m.w);
    }
#undef XCASE
#undef BODY
#undef M4A
    __syncthreads();

    // coalesced burst: 256 ch x 49 tasks; nontemporal -> don't evict xt from L2
    float* op = out + (size_t)(n * CCH + cg * 256) * 49;
    int c = t / 49, task = t - c * 49;
    for (int i = t; i < 256 * 49; i += 512) {
        __builtin_nontemporal_store(ob[task * OBSTR + c], &op[i]);
        task += 22; c += 10;                       // 512 = 10*49 + 22
        if (task >= 49) { task -= 49; c += 1; }
    }
}

// ---------- Fallback (direct) if ws too small ----------
__global__ __launch_bounds__(256) void roipool_direct(
    const float* __restrict__ x, const float* __restrict__ rois,
    float* __restrict__ out, int total)
{
    const int stride = gridDim.x * blockDim.x;
    for (int idx = blockIdx.x * blockDim.x + threadIdx.x; idx < total; idx += stride) {
        int n = idx / (CCH * 49), rem = idx - n * (CCH * 49);
        int c = rem / 49, pp = rem - c * 49;
        int ph = pp / 7, pw = pp - ph * 7;
        const float* r = rois + n * 4;
        int rx = (int)(r[0] * 0.0625f), ry = (int)(r[1] * 0.0625f);
        int sw = (int)(r[2] * 0.0625f) + 1, sh = (int)(r[3] * 0.0625f) + 1;
        int ys = ry + (ph * sh) / 7, ye = ry + ((ph + 1) * sh + 6) / 7;
        int xs = rx + (pw * sw) / 7, xe = rx + ((pw + 1) * sw + 6) / 7;
        const float* f = x + c * (HF * WF);
        float m = -INFINITY;
        for (int y = ys; y < ye; ++y)
            for (int xx = xs; xx < xe; ++xx)
                m = fmaxf(m, f[y * WF + xx]);
        out[idx] = m;
    }
}

extern "C" void kernel_launch(void* const* d_in, const int* in_sizes, int n_in,
                              void* d_out, int out_size, void* d_ws, size_t ws_size,
                              hipStream_t stream) {
    const float* x    = (const float*)d_in[0];   // (1, 512, 50, 50)
    const float* rois = (const float*)d_in[2];   // (256, 4)
    float* out = (float*)d_out;                  // (256, 512, 7, 7) fp32

    if (ws_size >= WS_NEEDED) {
        float* xt = (float*)d_ws;
        transpose_kernel<<<HF * 8, 256, 0, stream>>>(x, xt);
        roipool_t_kernel<<<NROI * 2, 512, 0, stream>>>(xt, rois, out);
    } else {
        const int total = NROI * CCH * 49;
        roipool_direct<<<2048, 256, 0, stream>>>(x, rois, out, total);
    }
}

// Round 7
// 33.583 us; speedup vs baseline: 51.6588x; 51.6588x over previous
//
#include <hip/hip_runtime.h>

#define CCH  512
#define HF   50
#define WF   50
#define NROI 256
#define WS_NEEDED (HF * WF * CCH * sizeof(float))   // 5.12 MB transposed map
#define ROWSTR (WF * 256)                           // floats between y rows (within cg256)
#define OBSTR 258                                   // LDS stage stride (floats)

// ---------- Kernel 1: transpose [C][H][W] -> [cg256][H][W][256] into ws ----------
__global__ __launch_bounds__(256) void transpose_kernel(
    const float* __restrict__ x, float* __restrict__ xt)
{
    __shared__ float tile[64][51];                 // odd stride: conflict-free
    const int y  = blockIdx.x >> 3;
    const int c0 = (blockIdx.x & 7) << 6;
    const int t  = threadIdx.x;
    const int wv = t >> 6, lane = t & 63;

    for (int r = 0; r < 16; ++r) {
        const int cl = wv * 16 + r;
        if (lane < WF)
            tile[cl][lane] = x[(c0 + cl) * (HF * WF) + y * WF + lane];
    }
    __syncthreads();

    const int g   = c0 >> 8;                       // 256-group id (0/1)
    const int cin = c0 & 255;
    for (int k = 0; k < 13; ++k) {
        const int xx = (t >> 6) + 4 * k;
        if (xx < WF)
            xt[((size_t)g * (HF * WF) + y * WF + xx) * 256 + cin + (t & 63)]
                = tile[t & 63][xx];
    }
}

// ---------- Kernel 2: pool from blocked-transposed map ----------
// Block = (n, cg of 256 ch, task-half): 1024 blocks x 512 threads.
// 4 blocks/CU resident (25.8 KB LDS) = 32 waves/CU. Lanes = channels (float4).
// xspan switch (5 cases) + 2-deep y software pipeline: next row's loads issue
// before current row's wait -> per-row latency ~halved, no spill (<=10 f4 live).
__global__ __launch_bounds__(512, 4) void roipool_t_kernel(
    const float* __restrict__ xt,
    const float* __restrict__ rois,
    float* __restrict__ out)
{
    __shared__ float ob[25 * OBSTR];               // 25.8 KB staged outputs

    const int n  = blockIdx.x >> 2;
    const int cg = blockIdx.x & 1;                 // alternates with XCD parity
    const int h  = (blockIdx.x >> 1) & 1;          // task half: 0 -> 0..24, 1 -> 25..48
    const int t  = threadIdx.x;
    const int wv = t >> 6, lane = t & 63;
    const int t0 = h * 25;
    const int cnt = 25 - h;                        // 25 or 24 tasks

    // scale 50/800 = 0.0625 exact; (int) trunc == jnp astype(int32)
    const float4 rv = *(const float4*)(rois + n * 4);
    const int rx = (int)(rv.x * 0.0625f);
    const int ry = (int)(rv.y * 0.0625f);
    const int sw = (int)(rv.z * 0.0625f) + 1;      // 6..23
    const int sh = (int)(rv.w * 0.0625f) + 1;      // 6..23

    const float* part = xt + (size_t)cg * (HF * WF * 256) + 4 * lane;

#define M4(a) { m.x = fmaxf(m.x,(a).x); m.y = fmaxf(m.y,(a).y); \
                m.z = fmaxf(m.z,(a).z); m.w = fmaxf(m.w,(a).w); }
#define LD(k) (*(const float4*)(rp + (k) * 256))

    for (int task = t0 + wv; task < t0 + cnt; task += 8) {
        const int ph = task / 7;
        const int pw = task - ph * 7;
        const int ys = ry + (ph * sh) / 7;
        const int ye = ry + ((ph + 1) * sh + 6) / 7;   // <= 47
        const int xs = rx + (pw * sw) / 7;
        const int xe = rx + ((pw + 1) * sw + 6) / 7;   // <= 47
        const int yspan = ye - ys;                     // 1..5
        const int xspan = xe - xs;                     // 1..5
        const float* rp = part + (ys * WF + xs) * 256;

        float4 m = make_float4(-INFINITY, -INFINITY, -INFINITY, -INFINITY);
        switch (xspan) {                               // wave-uniform scalar branch
        case 1: {
            float4 a0 = LD(0);
            for (int y = 1; y < yspan; ++y) {
                rp += ROWSTR; float4 b0 = LD(0);
                M4(a0); a0 = b0;
            }
            M4(a0);
        } break;
        case 2: {
            float4 a0 = LD(0), a1 = LD(1);
            for (int y = 1; y < yspan; ++y) {
                rp += ROWSTR; float4 b0 = LD(0), b1 = LD(1);
                M4(a0); M4(a1); a0 = b0; a1 = b1;
            }
            M4(a0); M4(a1);
        } break;
        case 3: {
            float4 a0 = LD(0), a1 = LD(1), a2 = LD(2);
            for (int y = 1; y < yspan; ++y) {
                rp += ROWSTR; float4 b0 = LD(0), b1 = LD(1), b2 = LD(2);
                M4(a0); M4(a1); M4(a2); a0 = b0; a1 = b1; a2 = b2;
            }
            M4(a0); M4(a1); M4(a2);
        } break;
        case 4: {
            float4 a0 = LD(0), a1 = LD(1), a2 = LD(2), a3 = LD(3);
            for (int y = 1; y < yspan; ++y) {
                rp += ROWSTR; float4 b0 = LD(0), b1 = LD(1), b2 = LD(2), b3 = LD(3);
                M4(a0); M4(a1); M4(a2); M4(a3);
                a0 = b0; a1 = b1; a2 = b2; a3 = b3;
            }
            M4(a0); M4(a1); M4(a2); M4(a3);
        } break;
        default: {
            float4 a0 = LD(0), a1 = LD(1), a2 = LD(2), a3 = LD(3), a4 = LD(4);
            for (int y = 1; y < yspan; ++y) {
                rp += ROWSTR; float4 b0 = LD(0), b1 = LD(1), b2 = LD(2), b3 = LD(3), b4 = LD(4);
                M4(a0); M4(a1); M4(a2); M4(a3); M4(a4);
                a0 = b0; a1 = b1; a2 = b2; a3 = b3; a4 = b4;
            }
            M4(a0); M4(a1); M4(a2); M4(a3); M4(a4);
        } break;
        }

        const int tl = task - t0;
        *(float2*)&ob[tl * OBSTR + 4 * lane]     = make_float2(m.x, m.y);
        *(float2*)&ob[tl * OBSTR + 4 * lane + 2] = make_float2(m.z, m.w);
    }
#undef LD
#undef M4
    __syncthreads();

    // coalesced burst: 256 ch x cnt tasks; nontemporal -> don't evict xt from L2
    float* op = out + (size_t)(n * CCH + cg * 256) * 49 + t0;
    if (h == 0) {
        for (int i = t; i < 256 * 25; i += 512) {
            const int c = i / 25, tl = i - c * 25;
            __builtin_nontemporal_store(ob[tl * OBSTR + c], &op[c * 49 + tl]);
        }
    } else {
        for (int i = t; i < 256 * 24; i += 512) {
            const int c = i / 24, tl = i - c * 24;
            __builtin_nontemporal_store(ob[tl * OBSTR + c], &op[c * 49 + tl]);
        }
    }
}

// ---------- Fallback (direct) if ws too small ----------
__global__ __launch_bounds__(256) void roipool_direct(
    const float* __restrict__ x, const float* __restrict__ rois,
    float* __restrict__ out, int total)
{
    const int stride = gridDim.x * blockDim.x;
    for (int idx = blockIdx.x * blockDim.x + threadIdx.x; idx < total; idx += stride) {
        int n = idx / (CCH * 49), rem = idx - n * (CCH * 49);
        int c = rem / 49, pp = rem - c * 49;
        int ph = pp / 7, pw = pp - ph * 7;
        const float* r = rois + n * 4;
        int rx = (int)(r[0] * 0.0625f), ry = (int)(r[1] * 0.0625f);
        int sw = (int)(r[2] * 0.0625f) + 1, sh = (int)(r[3] * 0.0625f) + 1;
        int ys = ry + (ph * sh) / 7, ye = ry + ((ph + 1) * sh + 6) / 7;
        int xs = rx + (pw * sw) / 7, xe = rx + ((pw + 1) * sw + 6) / 7;
        const float* f = x + c * (HF * WF);
        float m = -INFINITY;
        for (int y = ys; y < ye; ++y)
            for (int xx = xs; xx < xe; ++xx)
                m = fmaxf(m, f[y * WF + xx]);
        out[idx] = m;
    }
}

extern "C" void kernel_launch(void* const* d_in, const int* in_sizes, int n_in,
                              void* d_out, int out_size, void* d_ws, size_t ws_size,
                              hipStream_t stream) {
    const float* x    = (const float*)d_in[0];   // (1, 512, 50, 50)
    const float* rois = (const float*)d_in[2];   // (256, 4)
    float* out = (float*)d_out;                  // (256, 512, 7, 7) fp32

    if (ws_size >= WS_NEEDED) {
        float* xt = (float*)d_ws;
        transpose_kernel<<<HF * 8, 256, 0, stream>>>(x, xt);
        roipool_t_kernel<<<NROI * 4, 512, 0, stream>>>(xt, rois, out);
    } else {
        const int total = NROI * CCH * 49;
        roipool_direct<<<2048, 256, 0, stream>>>(x, rois, out, total);
    }
}

// Round 8
// 25.712 us; speedup vs baseline: 67.4733x; 1.3061x over previous
//
#include <hip/hip_runtime.h>

#define CCH  512
#define HF   50
#define WF   50
#define NROI 256
#define WS_NEEDED (HF * WF * CCH * sizeof(float))   // 5.12 MB transposed map
#define ROWSTR (WF * 256)                           // floats between y rows (within cg256)
#define OBSTR 258                                   // LDS stage stride (floats)

// ---------- Kernel 1: transpose [C][H][W] -> [cg256][H][W][256] into ws ----------
__global__ __launch_bounds__(256) void transpose_kernel(
    const float* __restrict__ x, float* __restrict__ xt)
{
    __shared__ float tile[64][51];                 // odd stride: conflict-free
    const int y  = blockIdx.x >> 3;
    const int c0 = (blockIdx.x & 7) << 6;
    const int t  = threadIdx.x;
    const int wv = t >> 6, lane = t & 63;

    for (int r = 0; r < 16; ++r) {
        const int cl = wv * 16 + r;
        if (lane < WF)
            tile[cl][lane] = x[(c0 + cl) * (HF * WF) + y * WF + lane];
    }
    __syncthreads();

    const int g   = c0 >> 8;                       // 256-group id (0/1)
    const int cin = c0 & 255;
    for (int k = 0; k < 13; ++k) {
        const int xx = (t >> 6) + 4 * k;
        if (xx < WF)
            xt[((size_t)g * (HF * WF) + y * WF + xx) * 256 + cin + (t & 63)]
                = tile[t & 63][xx];
    }
}

// ---------- Kernel 2: pool from blocked-transposed map ----------
// Block = (n, cg of 256 channels): 512 blocks x 512 threads (8 waves).
// Lanes = channels via float4; windows wave-uniform (zero divergence).
// Inner y-loop is a 2-deep rotating pipeline: row y+1's loads issue before
// row y's wait -> exposed L2/L3 latency per task ~halved. <=10 f4 live.
__global__ __launch_bounds__(512, 4) void roipool_t_kernel(
    const float* __restrict__ xt,
    const float* __restrict__ rois,
    float* __restrict__ out)
{
    __shared__ float ob[49 * OBSTR];               // 50.6 KB staged outputs

    const int n  = blockIdx.x >> 1;
    const int cg = blockIdx.x & 1;                 // one 2.56MB L2 partition per XCD parity
    const int t  = threadIdx.x;
    const int wv = t >> 6, lane = t & 63;

    // scale 50/800 = 0.0625 exact; (int) trunc == jnp astype(int32)
    const float4 rv = *(const float4*)(rois + n * 4);
    const int rx = (int)(rv.x * 0.0625f);
    const int ry = (int)(rv.y * 0.0625f);
    const int sw = (int)(rv.z * 0.0625f) + 1;      // 6..23
    const int sh = (int)(rv.w * 0.0625f) + 1;      // 6..23

    const float* part = xt + (size_t)cg * (HF * WF * 256) + 4 * lane;

#define M4(a) { m.x = fmaxf(m.x,(a).x); m.y = fmaxf(m.y,(a).y); \
                m.z = fmaxf(m.z,(a).z); m.w = fmaxf(m.w,(a).w); }
#define LD(k) (*(const float4*)(rp + (k) * 256))

    for (int task = wv; task < 49; task += 8) {
        const int ph = task / 7;
        const int pw = task - ph * 7;
        const int ys = ry + (ph * sh) / 7;
        const int ye = ry + ((ph + 1) * sh + 6) / 7;   // <= 47
        const int xs = rx + (pw * sw) / 7;
        const int xe = rx + ((pw + 1) * sw + 6) / 7;   // <= 47
        const int yspan = ye - ys;                     // 1..5
        const int xspan = xe - xs;                     // 1..5
        const float* rp = part + (ys * WF + xs) * 256;

        float4 m = make_float4(-INFINITY, -INFINITY, -INFINITY, -INFINITY);
        switch (xspan) {                               // wave-uniform scalar branch
        case 1: {
            float4 a0 = LD(0);
            for (int y = 1; y < yspan; ++y) {
                rp += ROWSTR; float4 b0 = LD(0);
                M4(a0); a0 = b0;
            }
            M4(a0);
        } break;
        case 2: {
            float4 a0 = LD(0), a1 = LD(1);
            for (int y = 1; y < yspan; ++y) {
                rp += ROWSTR; float4 b0 = LD(0), b1 = LD(1);
                M4(a0); M4(a1); a0 = b0; a1 = b1;
            }
            M4(a0); M4(a1);
        } break;
        case 3: {
            float4 a0 = LD(0), a1 = LD(1), a2 = LD(2);
            for (int y = 1; y < yspan; ++y) {
                rp += ROWSTR; float4 b0 = LD(0), b1 = LD(1), b2 = LD(2);
                M4(a0); M4(a1); M4(a2); a0 = b0; a1 = b1; a2 = b2;
            }
            M4(a0); M4(a1); M4(a2);
        } break;
        case 4: {
            float4 a0 = LD(0), a1 = LD(1), a2 = LD(2), a3 = LD(3);
            for (int y = 1; y < yspan; ++y) {
                rp += ROWSTR; float4 b0 = LD(0), b1 = LD(1), b2 = LD(2), b3 = LD(3);
                M4(a0); M4(a1); M4(a2); M4(a3);
                a0 = b0; a1 = b1; a2 = b2; a3 = b3;
            }
            M4(a0); M4(a1); M4(a2); M4(a3);
        } break;
        default: {
            float4 a0 = LD(0), a1 = LD(1), a2 = LD(2), a3 = LD(3), a4 = LD(4);
            for (int y = 1; y < yspan; ++y) {
                rp += ROWSTR; float4 b0 = LD(0), b1 = LD(1), b2 = LD(2), b3 = LD(3), b4 = LD(4);
                M4(a0); M4(a1); M4(a2); M4(a3); M4(a4);
                a0 = b0; a1 = b1; a2 = b2; a3 = b3; a4 = b4;
            }
            M4(a0); M4(a1); M4(a2); M4(a3); M4(a4);
        } break;
        }

        *(float2*)&ob[task * OBSTR + 4 * lane]     = make_float2(m.x, m.y);
        *(float2*)&ob[task * OBSTR + 4 * lane + 2] = make_float2(m.z, m.w);
    }
#undef LD
#undef M4
    __syncthreads();

    // coalesced contiguous burst: 256 ch x 49 tasks; nontemporal -> keep xt in L2
    float* op = out + (size_t)(n * CCH + cg * 256) * 49;
    int c = t / 49, task = t - c * 49;
    for (int i = t; i < 256 * 49; i += 512) {
        __builtin_nontemporal_store(ob[task * OBSTR + c], &op[i]);
        task += 22; c += 10;                       // 512 = 10*49 + 22
        if (task >= 49) { task -= 49; c += 1; }
    }
}

// ---------- Fallback (direct) if ws too small ----------
__global__ __launch_bounds__(256) void roipool_direct(
    const float* __restrict__ x, const float* __restrict__ rois,
    float* __restrict__ out, int total)
{
    const int stride = gridDim.x * blockDim.x;
    for (int idx = blockIdx.x * blockDim.x + threadIdx.x; idx < total; idx += stride) {
        int n = idx / (CCH * 49), rem = idx - n * (CCH * 49);
        int c = rem / 49, pp = rem - c * 49;
        int ph = pp / 7, pw = pp - ph * 7;
        const float* r = rois + n * 4;
        int rx = (int)(r[0] * 0.0625f), ry = (int)(r[1] * 0.0625f);
        int sw = (int)(r[2] * 0.0625f) + 1, sh = (int)(r[3] * 0.0625f) + 1;
        int ys = ry + (ph * sh) / 7, ye = ry + ((ph + 1) * sh + 6) / 7;
        int xs = rx + (pw * sw) / 7, xe = rx + ((pw + 1) * sw + 6) / 7;
        const float* f = x + c * (HF * WF);
        float m = -INFINITY;
        for (int y = ys; y < ye; ++y)
            for (int xx = xs; xx < xe; ++xx)
                m = fmaxf(m, f[y * WF + xx]);
        out[idx] = m;
    }
}

extern "C" void kernel_launch(void* const* d_in, const int* in_sizes, int n_in,
                              void* d_out, int out_size, void* d_ws, size_t ws_size,
                              hipStream_t stream) {
    const float* x    = (const float*)d_in[0];   // (1, 512, 50, 50)
    const float* rois = (const float*)d_in[2];   // (256, 4)
    float* out = (float*)d_out;                  // (256, 512, 7, 7) fp32

    if (ws_size >= WS_NEEDED) {
        float* xt = (float*)d_ws;
        transpose_kernel<<<HF * 8, 256, 0, stream>>>(x, xt);
        roipool_t_kernel<<<NROI * 2, 512, 0, stream>>>(xt, rois, out);
    } else {
        const int total = NROI * CCH * 49;
        roipool_direct<<<2048, 256, 0, stream>>>(x, rois, out, total);
    }
}